// Round 11
// baseline (74.618 us; speedup 1.0000x reference)
//
#include <hip/hip_runtime.h>
#include <cmath>

#define THREADS 256
#define QC 24000
#define NQ4 (QC / 4)
#define NCLS 80
#define NTOP 300
#define NHIST 4096
#define CAP 1024

typedef unsigned long long ull;
typedef float f32x4 __attribute__((ext_vector_type(4)));

// monotonic unsigned key for fp32 (total order matching float compare)
__device__ __forceinline__ unsigned fkey(float x) {
    unsigned b = __float_as_uint(x);
    return (b & 0x80000000u) ? ~b : (b | 0x80000000u);
}
__device__ __forceinline__ float fkey_inv(unsigned key) {
    unsigned b = (key & 0x80000000u) ? (key & 0x7fffffffu) : ~key;
    return __uint_as_float(b);
}
// Replicate float32 sigmoid: 1/(1+expf(-x)); double exp rounds to CR expf.
__device__ __forceinline__ float sigmoid_ref(float x) {
    float ef = (float)exp(-(double)x);
    return 1.0f / (1.0f + ef);
}

// Speculative static threshold: rank-300 logit ~2.24 for this data; 2.11
// keeps ~420 +- 20 candidates/row. Checked on-device; exact histogram
// fallback if violated.
#define T0 2.11f

// bitonic select: keep max iff (desc != up)
__device__ __forceinline__ unsigned csel32(bool desc, bool up, unsigned v, unsigned p) {
    unsigned mx = v > p ? v : p;
    unsigned mn = v > p ? p : v;
    return (desc != up) ? mx : mn;
}

__global__ __launch_bounds__(THREADS, 8) void postproc_kernel(
    const float* __restrict__ logits,   // [B, 300, 80]
    const float* __restrict__ pboxes,   // [B, 300, 4]
    const float* __restrict__ osizes,   // [B, 2]
    float* __restrict__ out_boxes,      // [B, 300, 4]
    float* __restrict__ out_labels,     // [B, 300]
    float* __restrict__ out_scores)     // [B, 300]
{
    const int b = blockIdx.x;
    const int tid = threadIdx.x;
    const int lane = tid & 63;
    const f32x4* __restrict__ row4 = (const f32x4*)(logits + (size_t)b * QC);

    __shared__ ull cand[CAP];               // 8 KB: (key<<32)|idx pairs
    __shared__ unsigned skey[512];          // 2 KB: sort keys / exchange buf
    __shared__ unsigned hist[NHIST / 2];    // 8 KB packed u16 (fallback only)
    __shared__ unsigned wsum[THREADS / 64];
    __shared__ int s_ncand;
    __shared__ unsigned s_thresh;

    if (tid == 0) s_ncand = 0;
    __syncthreads();

    auto pushe = [&](float x, int e) {
        if (x >= T0) {
            int p = atomicAdd(&s_ncand, 1);
            if (p < CAP)
                cand[p] = ((ull)fkey(x) << 32) | (ull)(unsigned)e;
        }
    };
    auto handle = [&](f32x4 v, int i) {
        pushe(v.x, 4 * i);     pushe(v.y, 4 * i + 1);
        pushe(v.z, 4 * i + 2); pushe(v.w, 4 * i + 3);
    };

    // ---- single streaming pass, 4 loads in flight ----
    int i = tid;
    for (; i + 3 * THREADS < NQ4; i += 4 * THREADS) {
        f32x4 a = row4[i];
        f32x4 b2 = row4[i + THREADS];
        f32x4 c2 = row4[i + 2 * THREADS];
        f32x4 d2 = row4[i + 3 * THREADS];
        handle(a, i);               handle(b2, i + THREADS);
        handle(c2, i + 2 * THREADS); handle(d2, i + 3 * THREADS);
    }
    for (; i < NQ4; i += THREADS) handle(row4[i], i);
    __syncthreads();
    int nc = s_ncand;

    // ---------------- FAST PATH: nc in [300, 512] ----------------
    if (nc >= NTOP && nc <= 512) {
        // sigmoid pass: pairs -> (sig<<32)|idx ; keys into registers
        unsigned e0 = 0u, e1 = 0u;
        if (tid < nc) {
            ull c = cand[tid];
            float sc = sigmoid_ref(fkey_inv((unsigned)(c >> 32)));
            unsigned kb = __float_as_uint(sc);
            cand[tid] = ((ull)kb << 32) | (c & 0xffffffffull);
            e0 = kb;
        }
        if (tid + 256 < nc) {
            ull c = cand[tid + 256];
            float sc = sigmoid_ref(fkey_inv((unsigned)(c >> 32)));
            unsigned kb = __float_as_uint(sc);
            cand[tid + 256] = ((ull)kb << 32) | (c & 0xffffffffull);
            e1 = kb;
        }
        __syncthreads();

        // ---- register bitonic-512 on u32 keys ----
        // elem0 index = tid, elem1 index = tid+256.
        #pragma unroll
        for (int k = 2; k <= 512; k <<= 1) {
            #pragma unroll
            for (int j = k >> 1; j > 0; j >>= 1) {
                if (j == 256) {
                    // in-thread; both elems desc -> e0=max, e1=min
                    unsigned mx = e0 > e1 ? e0 : e1;
                    unsigned mn = e0 > e1 ? e1 : e0;
                    e0 = mx; e1 = mn;
                } else if (j >= 64) {
                    // cross-wave via LDS
                    bool desc0 = (tid & k) == 0;
                    bool desc1 = ((tid + 256) & k) == 0;
                    bool up = (tid & j) != 0;
                    skey[tid] = e0; skey[tid + 256] = e1;
                    __syncthreads();
                    unsigned p0 = skey[tid ^ j];
                    unsigned p1 = skey[(tid + 256) ^ j];
                    __syncthreads();
                    e0 = csel32(desc0, up, e0, p0);
                    e1 = csel32(desc1, up, e1, p1);
                } else {
                    bool desc0 = (tid & k) == 0;
                    bool desc1 = ((tid + 256) & k) == 0;
                    bool up = (tid & j) != 0;
                    unsigned p0, p1;
                    if (j == 1) {          // DPP quad_perm [1,0,3,2]
                        p0 = (unsigned)__builtin_amdgcn_update_dpp(
                            (int)e0, (int)e0, 0xB1, 0xF, 0xF, false);
                        p1 = (unsigned)__builtin_amdgcn_update_dpp(
                            (int)e1, (int)e1, 0xB1, 0xF, 0xF, false);
                    } else if (j == 2) {   // DPP quad_perm [2,3,0,1]
                        p0 = (unsigned)__builtin_amdgcn_update_dpp(
                            (int)e0, (int)e0, 0x4E, 0xF, 0xF, false);
                        p1 = (unsigned)__builtin_amdgcn_update_dpp(
                            (int)e1, (int)e1, 0x4E, 0xF, 0xF, false);
                    } else if (j == 4) {   // ds_swizzle xor4
                        p0 = (unsigned)__builtin_amdgcn_ds_swizzle((int)e0, 0x101F);
                        p1 = (unsigned)__builtin_amdgcn_ds_swizzle((int)e1, 0x101F);
                    } else if (j == 8) {
                        p0 = (unsigned)__builtin_amdgcn_ds_swizzle((int)e0, 0x201F);
                        p1 = (unsigned)__builtin_amdgcn_ds_swizzle((int)e1, 0x201F);
                    } else if (j == 16) {
                        p0 = (unsigned)__builtin_amdgcn_ds_swizzle((int)e0, 0x401F);
                        p1 = (unsigned)__builtin_amdgcn_ds_swizzle((int)e1, 0x401F);
                    } else {               // j == 32: cross-half via bpermute
                        p0 = (unsigned)__shfl_xor((int)e0, 32, 64);
                        p1 = (unsigned)__shfl_xor((int)e1, 32, 64);
                    }
                    e0 = csel32(desc0, up, e0, p0);
                    e1 = csel32(desc1, up, e1, p1);
                }
            }
        }

        // dump sorted keys (descending) for rank lookup
        skey[tid] = e0;
        skey[tid + 256] = e1;
        __syncthreads();

        // ---- rank each candidate by binary search + idx tie-break; scatter ----
        const float o0 = osizes[2 * b], o1 = osizes[2 * b + 1];
        const float4* __restrict__ pb4 = (const float4*)pboxes + (size_t)b * NTOP;
        float4* __restrict__ ob4 = (float4*)out_boxes + (size_t)b * NTOP;

        auto rank_emit = [&](int sl) {
            ull c = cand[sl];
            unsigned kb = (unsigned)(c >> 32);
            unsigned idx = (unsigned)c;
            // first pos with skey[pos] <= kb  (= count of keys strictly greater)
            // search space [0,512] has 513 outcomes -> needs up to 10 steps
            int lo = 0, hi = 512;
            while (lo < hi) {
                int mid = (lo + hi) >> 1;
                if (skey[mid] > kb) lo = mid + 1; else hi = mid;
            }
            int pos = lo;
            // tie group? (duplicates adjacent in sorted array)
            if (lo + 1 < 512 && skey[lo + 1] == kb) {
                int cnt = 0;
                for (int j2 = 0; j2 < nc; ++j2) {
                    ull cj = cand[j2];
                    if ((unsigned)(cj >> 32) == kb && (unsigned)cj < idx) ++cnt;
                }
                pos = lo + cnt;
            }
            if (pos < NTOP) {
                float sc = __uint_as_float(kb);
                unsigned q = idx / NCLS;
                unsigned cls = idx - q * NCLS;
                out_scores[(size_t)b * NTOP + pos] = sc;
                out_labels[(size_t)b * NTOP + pos] = (float)cls;
                float4 pb = pb4[q];
                float4 ob;
                ob.x = (pb.x - 0.5f * pb.z) * o0;
                ob.y = (pb.y - 0.5f * pb.w) * o1;
                ob.z = (pb.x + 0.5f * pb.z) * o0;
                ob.w = (pb.y + 0.5f * pb.w) * o1;
                ob4[pos] = ob;
            }
        };
        if (tid < nc) rank_emit(tid);
        if (tid + 256 < nc) rank_emit(tid + 256);
        return;
    }

    // ---------------- SLOW PATHS (rare) ----------------
    if (nc < NTOP || nc > CAP) {
        // exact histogram threshold + re-collect
        for (int j = tid; j < NHIST / 2; j += THREADS) hist[j] = 0u;
        __syncthreads();
        for (int j = tid; j < NQ4; j += THREADS) {
            f32x4 v = row4[j];
            float vals[4] = {v.x, v.y, v.z, v.w};
            #pragma unroll
            for (int s = 0; s < 4; ++s) {
                unsigned bin = fkey(vals[s]) >> 20;
                atomicAdd(&hist[bin >> 1], (bin & 1) ? 0x10000u : 1u);
            }
        }
        __syncthreads();
        const int CHUNK = NHIST / THREADS;          // 16
        const int base = NHIST - 1 - tid * CHUNK;
        unsigned partial = 0;
        #pragma unroll
        for (int s = 0; s < CHUNK; ++s) {
            int bin = base - s;
            partial += (hist[bin >> 1] >> ((bin & 1) * 16)) & 0xffffu;
        }
        unsigned run = partial;
        #pragma unroll
        for (int d = 1; d < 64; d <<= 1) {
            unsigned v = __shfl_up(run, d, 64);
            if (lane >= d) run += v;
        }
        if (lane == 63) wsum[tid >> 6] = run;
        __syncthreads();
        unsigned off = 0;
        for (int w = 0; w < (tid >> 6); ++w) off += wsum[w];
        unsigned incl = run + off, excl = incl - partial;
        if (excl < NTOP && incl >= NTOP) {
            unsigned cum = excl;
            #pragma unroll
            for (int s = 0; s < CHUNK; ++s) {
                int bin = base - s;
                cum += (hist[bin >> 1] >> ((bin & 1) * 16)) & 0xffffu;
                if (cum >= NTOP) { s_thresh = (unsigned)bin << 20; break; }
            }
        }
        if (tid == 0) s_ncand = 0;
        __syncthreads();
        const unsigned T = s_thresh;
        for (int j = tid; j < NQ4; j += THREADS) {
            f32x4 v = row4[j];
            float vals[4] = {v.x, v.y, v.z, v.w};
            #pragma unroll
            for (int s = 0; s < 4; ++s) {
                unsigned kk = fkey(vals[s]);
                if (kk >= T) {
                    int pos = atomicAdd(&s_ncand, 1);
                    if (pos < CAP)
                        cand[pos] = ((ull)kk << 32) | (ull)(unsigned)(4 * j + s);
                }
            }
        }
        __syncthreads();
        nc = min(s_ncand, CAP);
    }

    // convert to composite (sig<<32)|~idx for tie-correct LDS sort
    for (int j = tid; j < nc; j += THREADS) {
        ull c = cand[j];
        float sc = sigmoid_ref(fkey_inv((unsigned)(c >> 32)));
        cand[j] = ((ull)__float_as_uint(sc) << 32) | (ull)(~(unsigned)c);
    }
    int npad = 512;
    while (npad < nc) npad <<= 1;
    for (int j = nc + tid; j < npad; j += THREADS) cand[j] = 0ull;
    __syncthreads();
    for (int k = 2; k <= npad; k <<= 1) {
        for (int j = k >> 1; j > 0; j >>= 1) {
            for (int t = tid; t < (npad >> 1); t += THREADS) {
                int u = ((t & ~(j - 1)) << 1) | (t & (j - 1));
                int uxj = u | j;
                ull a = cand[u], c = cand[uxj];
                bool desc = (u & k) == 0;
                if (desc ? (a < c) : (a > c)) { cand[u] = c; cand[uxj] = a; }
            }
            __syncthreads();
        }
    }
    const float o0 = osizes[2 * b], o1 = osizes[2 * b + 1];
    const float4* __restrict__ pb4 = (const float4*)pboxes + (size_t)b * NTOP;
    float4* __restrict__ ob4 = (float4*)out_boxes + (size_t)b * NTOP;
    for (int r = tid; r < NTOP; r += THREADS) {
        ull c = cand[r];
        float sc = __uint_as_float((unsigned)(c >> 32));
        unsigned idx = ~((unsigned)c);
        unsigned q = idx / NCLS;
        unsigned cls = idx - q * NCLS;
        out_scores[(size_t)b * NTOP + r] = sc;
        out_labels[(size_t)b * NTOP + r] = (float)cls;
        float4 pb = pb4[q];
        float4 ob;
        ob.x = (pb.x - 0.5f * pb.z) * o0;
        ob.y = (pb.y - 0.5f * pb.w) * o1;
        ob.z = (pb.x + 0.5f * pb.z) * o0;
        ob.w = (pb.y + 0.5f * pb.w) * o1;
        ob4[r] = ob;
    }
}

extern "C" void kernel_launch(void* const* d_in, const int* in_sizes, int n_in,
                              void* d_out, int out_size, void* d_ws, size_t ws_size,
                              hipStream_t stream) {
    const float* logits = (const float*)d_in[0];
    const float* pboxes = (const float*)d_in[1];
    const float* osizes = (const float*)d_in[2];
    const int B = in_sizes[2] / 2;

    float* out_boxes  = (float*)d_out;                       // B*300*4
    float* out_labels = out_boxes + (size_t)B * NTOP * 4;    // B*300
    float* out_scores = out_labels + (size_t)B * NTOP;       // B*300

    hipLaunchKernelGGL(postproc_kernel, dim3(B), dim3(THREADS), 0, stream,
                       logits, pboxes, osizes, out_boxes, out_labels, out_scores);
}